// Round 2
// baseline (445.920 us; speedup 1.0000x reference)
//
#include <hip/hip_runtime.h>
#include <hip/hip_bf16.h>
#include <math.h>

#define B   16
#define SQv 128   // seq_q
#define SK  256   // seq_k
#define HID 128
#define NH  4     // heads
#define DK  32    // head dim
#define DIM 64    // value dim
#define OUTD 128  // output dim

// kp[b,k,j] = bk[j] + sum_i key[b,k,i] * Wk[j,i]
__global__ __launch_bounds__(256) void proj_k_kernel(
    const float* __restrict__ key,
    const float* __restrict__ Wk,
    const float* __restrict__ bk,
    float* __restrict__ kp)
{
    int idx = blockIdx.x * blockDim.x + threadIdx.x;  // over B*SK*HID
    if (idx >= B * SK * HID) return;
    int j   = idx & (HID - 1);
    int row = idx >> 7;  // b*SK + k
    const float* krow = key + row * HID;
    const float* wrow = Wk + j * HID;
    float acc = bk[j];
#pragma unroll 8
    for (int i = 0; i < HID; ++i) acc += krow[i] * wrow[i];
    kp[idx] = acc;
}

// One block per (b, q): fused q-projection, scores, masked softmax, x, out-projection.
__global__ __launch_bounds__(256) void attn_kernel(
    const float* __restrict__ query,
    const float* __restrict__ Wq,
    const float* __restrict__ bq,
    const float* __restrict__ kp,
    const float* __restrict__ value,
    const int* __restrict__ mask,
    const float* __restrict__ Wo,
    const float* __restrict__ bo,
    float* __restrict__ out)
{
    const int bqi = blockIdx.x;       // b*SQ + q
    const int b   = bqi >> 7;
    const int t   = threadIdx.x;

    __shared__ float qrow[HID];
    __shared__ float qp[HID];
    __shared__ float e[NH][SK];       // scores, then exp(scores - max)
    __shared__ float maxv[NH];
    __shared__ float x[NH * DIM];

    // stage query row
    if (t < HID) qrow[t] = query[bqi * HID + t];
    __syncthreads();

    // q projection: thread j computes qp[j]
    if (t < HID) {
        const float* wrow = Wq + t * HID;
        float acc = bq[t];
#pragma unroll 8
        for (int i = 0; i < HID; ++i) acc += qrow[i] * wrow[i];
        qp[t] = acc;
    }
    __syncthreads();

    // scores: thread t handles k = t for all 4 heads
    {
        const float* krow = kp + (b * SK + t) * HID;
        const float scale = 0.17677669529663687f;  // 1/sqrt(32)
#pragma unroll
        for (int h = 0; h < NH; ++h) {
            float acc = 0.f;
#pragma unroll
            for (int d = 0; d < DK; ++d) acc += qp[h * DK + d] * krow[h * DK + d];
            e[h][t] = acc * scale;
        }
    }
    __syncthreads();

    // per-head max over k (4 threads scan serially; cheap)
    if (t < NH) {
        float m = e[t][0];
        for (int k = 1; k < SK; ++k) m = fmaxf(m, e[t][k]);
        maxv[t] = m;
    }
    __syncthreads();

#pragma unroll
    for (int h = 0; h < NH; ++h) e[h][t] = __expf(e[h][t] - maxv[h]);
    __syncthreads();

    // x[h,d] = sum_k e[h][k]*m[b,k,d]*v[b,k,d] / sum_k e[h][k]*m[b,k,d]
    {
        const int h = t >> 6;
        const int d = t & 63;
        const float* vcol = value + b * SK * DIM + d;
        const int*   mcol = mask  + b * SK * DIM + d;
        float num = 0.f, den = 0.f;
        for (int k = 0; k < SK; ++k) {
            float w = e[h][k];
            if (mcol[k * DIM] != 0) {
                num += w * vcol[k * DIM];
                den += w;
            }
        }
        x[t] = num / den;
    }
    __syncthreads();

    // output projection: thread o < 128 computes out[b,q,o]
    if (t < OUTD) {
        const float* wrow = Wo + t * (NH * DIM);
        float acc = bo[t];
#pragma unroll 8
        for (int j = 0; j < NH * DIM; ++j) acc += x[j] * wrow[j];
        out[bqi * OUTD + t] = acc;
    }
}

extern "C" void kernel_launch(void* const* d_in, const int* in_sizes, int n_in,
                              void* d_out, int out_size, void* d_ws, size_t ws_size,
                              hipStream_t stream)
{
    const float* query = (const float*)d_in[0];
    const float* key   = (const float*)d_in[1];
    const float* value = (const float*)d_in[2];
    const int*   mask  = (const int*)d_in[3];
    const float* Wq    = (const float*)d_in[4];
    const float* bq    = (const float*)d_in[5];
    const float* Wk    = (const float*)d_in[6];
    const float* bk    = (const float*)d_in[7];
    const float* Wo    = (const float*)d_in[8];
    const float* bo    = (const float*)d_in[9];
    float* out = (float*)d_out;

    float* kp = (float*)d_ws;  // B*SK*HID fp32 = 2 MB

    proj_k_kernel<<<(B * SK * HID + 255) / 256, 256, 0, stream>>>(key, Wk, bk, kp);
    attn_kernel<<<B * SQv, 256, 0, stream>>>(query, Wq, bq, kp, value, mask, Wo, bo, out);
}

// Round 3
// 148.406 us; speedup vs baseline: 3.0047x; 3.0047x over previous
//
#include <hip/hip_runtime.h>
#include <hip/hip_bf16.h>
#include <math.h>

#define B    16
#define SQv  128   // seq_q
#define SK   256   // seq_k
#define HID  128
#define NH   4     // heads
#define DK   32    // head dim
#define DIM  64    // value dim
#define OUTD 128   // output dim

// ---------------------------------------------------------------------------
// Transpose the three weight matrices so all later reads are lane-coalesced.
//   z=0: Wq (128x128) -> Wq_t[i][j]
//   z=1: Wk (128x128) -> Wk_t[i][j]
//   z=2: Wo (128x256) -> Wo_t[j][o]
// dst[c*R + r] = src[r*C + c]
__global__ __launch_bounds__(256) void transpose3_kernel(
    const float* __restrict__ Wq, const float* __restrict__ Wk,
    const float* __restrict__ Wo,
    float* __restrict__ Wq_t, float* __restrict__ Wk_t, float* __restrict__ Wo_t)
{
    __shared__ float tile[16][17];
    const int z = blockIdx.z;
    const float* src; float* dst; int R, C;
    if (z == 0)      { src = Wq; dst = Wq_t; R = 128; C = 128; }
    else if (z == 1) { src = Wk; dst = Wk_t; R = 128; C = 128; }
    else             { src = Wo; dst = Wo_t; R = 128; C = 256; }
    const int c0 = blockIdx.x * 16, r0 = blockIdx.y * 16;
    if (c0 >= C) return;                       // block-uniform
    const int tx = threadIdx.x & 15, ty = threadIdx.x >> 4;
    tile[ty][tx] = src[(r0 + ty) * C + (c0 + tx)];
    __syncthreads();
    dst[(c0 + ty) * R + (r0 + tx)] = tile[tx][ty];
}

// ---------------------------------------------------------------------------
// kp_t[b][j][k] = bk[j] + sum_i key[b,k,i] * Wk[j,i]
// Reads: key row broadcast (wave-uniform float4), Wk_t coalesced.
// Writes: scattered (fire-and-forget).
__global__ __launch_bounds__(256) void proj_k_kernel(
    const float* __restrict__ key,
    const float* __restrict__ Wk_t,
    const float* __restrict__ bk,
    float* __restrict__ kp_t)
{
    const int idx = blockIdx.x * 256 + threadIdx.x;   // over B*SK*HID
    const int j   = idx & (HID - 1);
    const int row = idx >> 7;                         // b*SK + k
    const float4* krow4 = (const float4*)(key + row * HID);
    float acc = bk[j];
#pragma unroll
    for (int i4 = 0; i4 < HID / 4; ++i4) {
        float4 kv = krow4[i4];
        const float* w = Wk_t + (i4 * 4) * HID + j;
        acc += kv.x * w[0] + kv.y * w[HID] + kv.z * w[2 * HID] + kv.w * w[3 * HID];
    }
    const int b = row >> 8, k = row & (SK - 1);
    kp_t[(b * HID + j) * SK + k] = acc;
}

// ---------------------------------------------------------------------------
// One block per (b, q).
__global__ __launch_bounds__(256) void attn_kernel(
    const float* __restrict__ query,
    const float* __restrict__ Wq_t,
    const float* __restrict__ bq,
    const float* __restrict__ kp_t,
    const float* __restrict__ value,
    const int* __restrict__ mask,
    const float* __restrict__ Wo_t,
    const float* __restrict__ bo,
    float* __restrict__ out)
{
    const int bqi = blockIdx.x;        // b*SQ + q
    const int b   = bqi >> 7;
    const int t   = threadIdx.x;

    __shared__ float qrow[HID];
    __shared__ float qp[HID];
    __shared__ float e[NH][SK];
    __shared__ float maxv[NH];
    __shared__ float x[NH * DIM];

    if (t < HID) qrow[t] = query[bqi * HID + t];
    __syncthreads();

    // q projection: lane j, Wq_t coalesced, qrow broadcast float4
    if (t < HID) {
        float acc = bq[t];
        const float4* q4 = (const float4*)qrow;
#pragma unroll
        for (int i4 = 0; i4 < HID / 4; ++i4) {
            float4 qv = q4[i4];
            const float* w = Wq_t + (i4 * 4) * HID + t;
            acc += qv.x * w[0] + qv.y * w[HID] + qv.z * w[2 * HID] + qv.w * w[3 * HID];
        }
        qp[t] = acc;
    }
    __syncthreads();

    // scores: lane t = k (0..255); kp_t coalesced along k, qp broadcast float4
    {
        const float scale = 0.17677669529663687f;  // 1/sqrt(32)
        const float4* qp4 = (const float4*)qp;
#pragma unroll
        for (int h = 0; h < NH; ++h) {
            float acc = 0.f;
            const float* kb = kp_t + (b * HID + h * DK) * SK + t;
#pragma unroll
            for (int d4 = 0; d4 < DK / 4; ++d4) {
                float4 qv = qp4[h * (DK / 4) + d4];
                const float* kk = kb + (d4 * 4) * SK;
                acc += qv.x * kk[0] + qv.y * kk[SK] + qv.z * kk[2 * SK] + qv.w * kk[3 * SK];
            }
            e[h][t] = acc * scale;
        }
    }
    __syncthreads();

    // per-head max: butterfly over 64 lanes
    {
        const int h = t >> 6, k0 = t & 63;
        float m = fmaxf(fmaxf(e[h][k0], e[h][k0 + 64]),
                        fmaxf(e[h][k0 + 128], e[h][k0 + 192]));
#pragma unroll
        for (int off = 32; off > 0; off >>= 1) m = fmaxf(m, __shfl_xor(m, off, 64));
        if (k0 == 0) maxv[h] = m;
    }
    __syncthreads();

#pragma unroll
    for (int h = 0; h < NH; ++h) e[h][t] = __expf(e[h][t] - maxv[h]);
    __syncthreads();

    // num/den: thread = (h, d); value/mask coalesced, e broadcast float4
    {
        const int h = t >> 6, d = t & 63;
        const float* vcol = value + b * SK * DIM + d;
        const int*   mcol = mask  + b * SK * DIM + d;
        float num = 0.f, den = 0.f;
        const float4* e4 = (const float4*)e[h];
#pragma unroll 8
        for (int k4 = 0; k4 < SK / 4; ++k4) {
            float4 ew = e4[k4];
            const int kb = k4 * 4;
            {
                float wm = mcol[(kb + 0) * DIM] ? ew.x : 0.f;
                num = fmaf(wm, vcol[(kb + 0) * DIM], num); den += wm;
            }
            {
                float wm = mcol[(kb + 1) * DIM] ? ew.y : 0.f;
                num = fmaf(wm, vcol[(kb + 1) * DIM], num); den += wm;
            }
            {
                float wm = mcol[(kb + 2) * DIM] ? ew.z : 0.f;
                num = fmaf(wm, vcol[(kb + 2) * DIM], num); den += wm;
            }
            {
                float wm = mcol[(kb + 3) * DIM] ? ew.w : 0.f;
                num = fmaf(wm, vcol[(kb + 3) * DIM], num); den += wm;
            }
        }
        x[t] = num / den;
    }
    __syncthreads();

    // output projection: lane o; Wo_t coalesced, x broadcast float4
    if (t < OUTD) {
        float acc = bo[t];
        const float4* x4 = (const float4*)x;
#pragma unroll
        for (int j4 = 0; j4 < (NH * DIM) / 4; ++j4) {
            float4 xv = x4[j4];
            const float* w = Wo_t + (j4 * 4) * OUTD + t;
            acc += xv.x * w[0] + xv.y * w[OUTD] + xv.z * w[2 * OUTD] + xv.w * w[3 * OUTD];
        }
        out[bqi * OUTD + t] = acc;
    }
}

extern "C" void kernel_launch(void* const* d_in, const int* in_sizes, int n_in,
                              void* d_out, int out_size, void* d_ws, size_t ws_size,
                              hipStream_t stream)
{
    const float* query = (const float*)d_in[0];
    const float* key   = (const float*)d_in[1];
    const float* value = (const float*)d_in[2];
    const int*   mask  = (const int*)d_in[3];
    const float* Wq    = (const float*)d_in[4];
    const float* bq    = (const float*)d_in[5];
    const float* Wk    = (const float*)d_in[6];
    const float* bk    = (const float*)d_in[7];
    const float* Wo    = (const float*)d_in[8];
    const float* bo    = (const float*)d_in[9];
    float* out = (float*)d_out;

    float* ws   = (float*)d_ws;
    float* Wq_t = ws;                       // 128*128
    float* Wk_t = Wq_t + HID * HID;         // 128*128
    float* Wo_t = Wk_t + HID * HID;         // 256*128
    float* kp_t = Wo_t + (NH * DIM) * OUTD; // B*HID*SK fp32 = 2 MB

    transpose3_kernel<<<dim3(16, 8, 3), 256, 0, stream>>>(Wq, Wk, Wo, Wq_t, Wk_t, Wo_t);
    proj_k_kernel<<<(B * SK * HID) / 256, 256, 0, stream>>>(key, Wk_t, bk, kp_t);
    attn_kernel<<<B * SQv, 256, 0, stream>>>(query, Wq_t, bq, kp_t, value, mask, Wo_t, bo, out);
}

// Round 4
// 126.586 us; speedup vs baseline: 3.5227x; 1.1724x over previous
//
#include <hip/hip_runtime.h>
#include <math.h>

#define B    16
#define SQn  128   // seq_q
#define SEQK 256   // seq_k
#define HID  128
#define NH   4     // heads
#define DK   32    // head dim
#define DIM  64    // value dim
#define OUTD 128   // output dim

// ---------------------------------------------------------------------------
// Transpose weights: Wq(128x128)->Wq_t[i][j], Wk->Wk_t, Wo(128x256)->Wo_t[j][o]
__global__ __launch_bounds__(256) void transpose3_kernel(
    const float* __restrict__ Wq, const float* __restrict__ Wk,
    const float* __restrict__ Wo,
    float* __restrict__ Wq_t, float* __restrict__ Wk_t, float* __restrict__ Wo_t)
{
    __shared__ float tile[16][17];
    const int z = blockIdx.z;
    const float* src; float* dst; int R, C;
    if (z == 0)      { src = Wq; dst = Wq_t; R = 128; C = 128; }
    else if (z == 1) { src = Wk; dst = Wk_t; R = 128; C = 128; }
    else             { src = Wo; dst = Wo_t; R = 128; C = 256; }
    const int c0 = blockIdx.x * 16, r0 = blockIdx.y * 16;
    if (c0 >= C) return;
    const int tx = threadIdx.x & 15, ty = threadIdx.x >> 4;
    tile[ty][tx] = src[(r0 + ty) * C + (c0 + tx)];
    __syncthreads();
    dst[(c0 + ty) * R + (r0 + tx)] = tile[tx][ty];
}

// ---------------------------------------------------------------------------
// prep: MVF[b][k][d] = mask? value:0 ; MVF[b][k][64+d] = mask? 1:0 ; out = bo
__global__ __launch_bounds__(256) void prep_kernel(
    const float* __restrict__ value, const int* __restrict__ mask,
    const float* __restrict__ bo, float* __restrict__ MVF, float* __restrict__ out)
{
    const int idx = blockIdx.x * 256 + threadIdx.x;
    const int NMV = B * SEQK * DIM;  // 262144
    if (idx < NMV) {
        const int d = idx & 63, rest = idx >> 6;     // rest = b*256+k
        const float v = value[idx];
        const int   m = mask[idx];
        MVF[rest * 128 + d]      = m ? v : 0.f;
        MVF[rest * 128 + 64 + d] = m ? 1.f : 0.f;
    } else {
        const int o = idx - NMV;                     // < 262144
        out[o] = bo[o & 127];
    }
}

// ---------------------------------------------------------------------------
// Both projections. Rows 0..2047 = query -> qp[row][j] (scaled by 1/sqrt(32)),
// rows 2048..6143 = key -> kp_t[(b*128+j)*256+k].
__global__ __launch_bounds__(256) void projqk_kernel(
    const float* __restrict__ query, const float* __restrict__ key,
    const float* __restrict__ Wq_t, const float* __restrict__ Wk_t,
    const float* __restrict__ bq, const float* __restrict__ bk,
    float* __restrict__ qp, float* __restrict__ kp_t)
{
    __shared__ float in16[16 * 128];
    const int r0 = blockIdx.x * 16;
    const bool isQ = (r0 < 2048);
    const int t = threadIdx.x;

    const float4* src4 = (const float4*)(isQ ? (query + r0 * 128)
                                             : (key + (r0 - 2048) * 128));
    float4* in4 = (float4*)in16;
    in4[t]       = src4[t];
    in4[t + 256] = src4[t + 256];
    __syncthreads();

    const int j  = t & 127;
    const int rg = (t >> 7) * 8;
    const float* W = isQ ? Wq_t : Wk_t;
    const float bias = isQ ? bq[j] : bk[j];
    float acc[8];
#pragma unroll
    for (int r = 0; r < 8; ++r) acc[r] = bias;

    for (int i4 = 0; i4 < 32; ++i4) {
        const float w0 = W[(i4 * 4 + 0) * 128 + j];
        const float w1 = W[(i4 * 4 + 1) * 128 + j];
        const float w2 = W[(i4 * 4 + 2) * 128 + j];
        const float w3 = W[(i4 * 4 + 3) * 128 + j];
#pragma unroll
        for (int r = 0; r < 8; ++r) {
            float4 xv = ((const float4*)(in16 + (rg + r) * 128))[i4];
            acc[r] = fmaf(xv.x, w0, fmaf(xv.y, w1, fmaf(xv.z, w2, fmaf(xv.w, w3, acc[r]))));
        }
    }

    if (isQ) {
        const float scale = 0.17677669529663687f;  // 1/sqrt(32) folded into qp
#pragma unroll
        for (int r = 0; r < 8; ++r) qp[(r0 + rg + r) * 128 + j] = acc[r] * scale;
    } else {
#pragma unroll
        for (int r = 0; r < 8; ++r) {
            const int row = r0 - 2048 + rg + r;
            const int bb = row >> 8, k = row & 255;
            kp_t[(bb * 128 + j) * 256 + k] = acc[r];
        }
    }
}

// ---------------------------------------------------------------------------
// Fused attention + O-projection partial. Block = (qtile, h, b), 256 threads.
__global__ __launch_bounds__(256) void attn_kernel(
    const float* __restrict__ qp, const float* __restrict__ kp_t,
    const float* __restrict__ MVF, const float* __restrict__ Wo_t,
    float* __restrict__ out)
{
    const int qt = blockIdx.x, h = blockIdx.y, b = blockIdx.z;
    const int q0 = qt * 32;
    const int t  = threadIdx.x;

    __shared__ float qs[32 * 33];    // qs[i][q]
    __shared__ float es[256 * 36];   // es[k][q], 36 floats = 9 float4 per row
    __shared__ float red[8 * 33];
    __shared__ float xs[32 * 68];    // xs[q][c], 68 floats = 17 float4 per row

    // stage q fragment transposed: qp[b*128+q0+q][h*32+i] -> qs[i*33+q]
    {
        const int i = t & 31, qq = t >> 5;
#pragma unroll
        for (int it = 0; it < 4; ++it) {
            const int q = qq + it * 8;
            qs[i * 33 + q] = qp[(b * 128 + q0 + q) * 128 + h * 32 + i];
        }
    }
    __syncthreads();

    // GEMM1: S[q][kg*32..+32], thread = (q = t&31, kg = t>>5)
    const int q = t & 31, kg = t >> 5;
    float s[32];
#pragma unroll
    for (int n = 0; n < 32; ++n) s[n] = 0.f;
    {
        const float4* kpb = (const float4*)(kp_t + (b * 128 + h * 32) * 256) + kg * 8;
        for (int i = 0; i < 32; ++i) {
            const float qv = qs[i * 33 + q];
            const float4* kr = kpb + i * 64;
#pragma unroll
            for (int n = 0; n < 8; ++n) {
                const float4 kv = kr[n];
                s[n * 4 + 0] = fmaf(qv, kv.x, s[n * 4 + 0]);
                s[n * 4 + 1] = fmaf(qv, kv.y, s[n * 4 + 1]);
                s[n * 4 + 2] = fmaf(qv, kv.z, s[n * 4 + 2]);
                s[n * 4 + 3] = fmaf(qv, kv.w, s[n * 4 + 3]);
            }
        }
    }

    // row max over k: per-thread max, then 8-way partials in LDS
    {
        float m = s[0];
#pragma unroll
        for (int n = 1; n < 32; ++n) m = fmaxf(m, s[n]);
        red[kg * 33 + q] = m;
    }
    __syncthreads();
    {
        float m = red[q];
#pragma unroll
        for (int rr = 1; rr < 8; ++rr) m = fmaxf(m, red[rr * 33 + q]);
#pragma unroll
        for (int n = 0; n < 32; ++n) es[(kg * 32 + n) * 36 + q] = __expf(s[n] - m);
    }
    __syncthreads();

    // GEMM2: num/den. Thread = (c = t&63, wave qg = t>>6 handles q = qg*8..+8)
    const int c = t & 63, qg = t >> 6;
    float num[8], den[8];
#pragma unroll
    for (int i = 0; i < 8; ++i) { num[i] = 0.f; den[i] = 0.f; }
    {
        const float*  mvp = MVF + (b * 256) * 128 + c;
        const float4* e4  = (const float4*)es + qg * 2;
        for (int k = 0; k < 256; ++k) {
            const float4 e0 = e4[k * 9];
            const float4 e1 = e4[k * 9 + 1];
            const float mvv = mvp[k * 128];
            const float mff = mvp[k * 128 + 64];
            num[0] = fmaf(e0.x, mvv, num[0]); den[0] = fmaf(e0.x, mff, den[0]);
            num[1] = fmaf(e0.y, mvv, num[1]); den[1] = fmaf(e0.y, mff, den[1]);
            num[2] = fmaf(e0.z, mvv, num[2]); den[2] = fmaf(e0.z, mff, den[2]);
            num[3] = fmaf(e0.w, mvv, num[3]); den[3] = fmaf(e0.w, mff, den[3]);
            num[4] = fmaf(e1.x, mvv, num[4]); den[4] = fmaf(e1.x, mff, den[4]);
            num[5] = fmaf(e1.y, mvv, num[5]); den[5] = fmaf(e1.y, mff, den[5]);
            num[6] = fmaf(e1.z, mvv, num[6]); den[6] = fmaf(e1.z, mff, den[6]);
            num[7] = fmaf(e1.w, mvv, num[7]); den[7] = fmaf(e1.w, mff, den[7]);
        }
    }
#pragma unroll
    for (int i = 0; i < 8; ++i) xs[(qg * 8 + i) * 68 + c] = num[i] / den[i];
    __syncthreads();

    // GEMM3: partial O-projection for this head slice; atomic accumulate.
    const int o  = t & 127;
    const int qh = (t >> 7) * 16;
    float acc[16];
#pragma unroll
    for (int i = 0; i < 16; ++i) acc[i] = 0.f;
    {
        const float* wo = Wo_t + (h * 64) * 128 + o;
        for (int j4 = 0; j4 < 16; ++j4) {
            const float w0 = wo[(j4 * 4 + 0) * 128];
            const float w1 = wo[(j4 * 4 + 1) * 128];
            const float w2 = wo[(j4 * 4 + 2) * 128];
            const float w3 = wo[(j4 * 4 + 3) * 128];
#pragma unroll
            for (int i = 0; i < 16; ++i) {
                const float4 xv = ((const float4*)(xs + (qh + i) * 68))[j4];
                acc[i] = fmaf(xv.x, w0, fmaf(xv.y, w1, fmaf(xv.z, w2, fmaf(xv.w, w3, acc[i]))));
            }
        }
    }
#pragma unroll
    for (int i = 0; i < 16; ++i)
        atomicAdd(out + (b * 128 + q0 + qh + i) * 128 + o, acc[i]);
}

extern "C" void kernel_launch(void* const* d_in, const int* in_sizes, int n_in,
                              void* d_out, int out_size, void* d_ws, size_t ws_size,
                              hipStream_t stream)
{
    const float* query = (const float*)d_in[0];
    const float* key   = (const float*)d_in[1];
    const float* value = (const float*)d_in[2];
    const int*   mask  = (const int*)d_in[3];
    const float* Wq    = (const float*)d_in[4];
    const float* bq    = (const float*)d_in[5];
    const float* Wk    = (const float*)d_in[6];
    const float* bk    = (const float*)d_in[7];
    const float* Wo    = (const float*)d_in[8];
    const float* bo    = (const float*)d_in[9];
    float* out = (float*)d_out;

    float* ws   = (float*)d_ws;
    float* Wq_t = ws;                         // 16384
    float* Wk_t = Wq_t + HID * HID;           // 16384
    float* Wo_t = Wk_t + HID * HID;           // 32768
    float* qp   = Wo_t + 256 * 128;           // 2048*128 = 262144
    float* kp_t = qp + 2048 * 128;            // 16*128*256 = 524288
    float* MVF  = kp_t + 524288;              // 16*256*128 = 524288

    transpose3_kernel<<<dim3(16, 8, 3), 256, 0, stream>>>(Wq, Wk, Wo, Wq_t, Wk_t, Wo_t);
    prep_kernel<<<(2 * B * SEQK * DIM) / 256, 256, 0, stream>>>(value, mask, bo, MVF, out);
    projqk_kernel<<<6144 / 16, 256, 0, stream>>>(query, key, Wq_t, Wk_t, bq, bk, qp, kp_t);
    attn_kernel<<<dim3(4, NH, B), 256, 0, stream>>>(qp, kp_t, MVF, Wo_t, out);
}